// Round 5
// baseline (48.838 us; speedup 1.0000x reference)
//
#include <hip/hip_runtime.h>
#include <hip/hip_bf16.h>
#include <stdint.h>

// Problem constants
#define B_SZ   4096
#define IN_SZ  256
#define U_SZ   128
#define G_SZ   1000
#define LW_SZ  64
#define LB_SZ  32
#define K_SZ   (LW_SZ * IN_SZ)      // 16384

// GEMM tiling: out[B, U] = A[B, K] * Wf[K, U]
// A[b, l*256+i] = zw[b, l] * x[b, i]; zw applied via pk_mul on A-fragments.
#define BM     128
#define BK     64
#define KSPL   16                   // split-K over l: 4 l's per block
#define NSTEP  16                   // 4 chunks (i) x 4 li
#define NTILE  (K_SZ / BK)          // 256 wfT k-tiles
#define CHUNK  (BK * U_SZ)          // 8192 shorts per staged tile (16 KB)

typedef __attribute__((ext_vector_type(8))) short  bf16x8;
typedef __attribute__((ext_vector_type(4))) float  f32x4;
typedef __attribute__((ext_vector_type(8))) _Float16 f16x8;
typedef __attribute__((ext_vector_type(2))) _Float16 f16x2;
typedef __attribute__((ext_vector_type(4))) _Float16 f16x4;

typedef const void __attribute__((address_space(1)))* gas_ptr;
typedef void __attribute__((address_space(3)))* las_ptr;

__device__ __forceinline__ ushort f2bf(float f) {
    unsigned u = __float_as_uint(f);
    u += 0x7fffu + ((u >> 16) & 1u);
    return (ushort)(u >> 16);
}

__device__ __forceinline__ float softplus_f(float v) {
    return fmaxf(v, 0.0f) + log1pf(__expf(-fabsf(v)));
}

// ---------------------------------------------------------------------------
// Prep (fused): blocks 0..255 convert Wf -> wfT (f16, transposed to Bs[u][k]
// layout, XOR swizzle pre-applied); blocks 256..383 convert x -> xh (f16,
// per-(mtile,chunk), swizzle pre-applied). LDS stride 133 (132 gave an 8-way
// bank conflict on the transpose read: 8-row stride x 132 floats = 0 mod 32).
// ---------------------------------------------------------------------------
__global__ __launch_bounds__(256) void fmd_prep(
    const float* __restrict__ Wf, const float* __restrict__ x,
    short* __restrict__ wfT, short* __restrict__ xh)
{
    const int tid = threadIdx.x;
    if (blockIdx.x < NTILE) {
        const int t = blockIdx.x;               // k-tile 0..255
        __shared__ float lds[64 * 133];         // [kk][u], pad 133
        #pragma unroll
        for (int it = 0; it < 8; ++it) {
            int idx = it * 256 + tid;           // 2048 float4 slots
            int kk = idx >> 5, u4 = idx & 31;
            float4 v = *reinterpret_cast<const float4*>(&Wf[(t * 64 + kk) * U_SZ + u4 * 4]);
            *reinterpret_cast<float4*>(&lds[kk * 133 + u4 * 4]) = v;
        }
        __syncthreads();
        short* chunk = wfT + t * CHUNK;
        #pragma unroll
        for (int g = 0; g < 4; ++g) {
            int p = g * 2048 + tid * 8;
            int u = p >> 6;
            int cc = p & 63;
            int kk0 = cc ^ ((u & 7) << 3);      // swizzle bits 3..5; cc is 8-aligned
            union { _Float16 h[8]; f16x8 v; } pk;
            #pragma unroll
            for (int j = 0; j < 8; ++j)
                pk.h[j] = (_Float16)lds[(kk0 + j) * 133 + u];
            *reinterpret_cast<f16x8*>(&chunk[p]) = pk.v;
        }
    } else {
        const int bb = blockIdx.x - NTILE;      // 0..127 : (mtile, chunk)
        const int mt = bb >> 2, c = bb & 3;
        short* chunk = xh + bb * CHUNK;
        #pragma unroll
        for (int g = 0; g < 4; ++g) {
            int p = g * 2048 + tid * 8;
            int r = p >> 6;
            int cc0 = (p & 63) ^ ((r & 7) << 3);
            const float* src = &x[(mt * BM + r) * IN_SZ + c * 64 + cc0];
            float4 a = *reinterpret_cast<const float4*>(src);
            float4 b = *reinterpret_cast<const float4*>(src + 4);
            union { _Float16 h[8]; f16x8 v; } pk;
            pk.h[0] = (_Float16)a.x; pk.h[1] = (_Float16)a.y;
            pk.h[2] = (_Float16)a.z; pk.h[3] = (_Float16)a.w;
            pk.h[4] = (_Float16)b.x; pk.h[5] = (_Float16)b.y;
            pk.h[6] = (_Float16)b.z; pk.h[7] = (_Float16)b.w;
            *reinterpret_cast<f16x8*>(&chunk[p]) = pk.v;
        }
    }
}

// ---------------------------------------------------------------------------
// GEMM v5: 512 blocks (32 mt x 16 ks), 4 waves, 64x64 wave tile.
// - A-fragments loaded to REGISTERS once per c-chunk, reused across 4 li
//   with per-li pk_mul zw scaling (LDS reads 16->10 KB/wave/step).
// - As single-buffered (freed after li==0 reg-load), Bs triple-buffered,
//   B[s+2] prefetch, counted vmcnt {4,8,8,4}, never 0 mid-loop.
// - Partials stored NON-TEMPORAL (don't thrash L2 that holds wfT/xh).
// ---------------------------------------------------------------------------
__global__ __launch_bounds__(256, 2) void fmd_gemm5(
    const short* __restrict__ xh,
    const short* __restrict__ wfT,
    const float* __restrict__ zw_mu,
    const float* __restrict__ zw_sigma,
    const float* __restrict__ eps_w,
    const int*   __restrict__ gid,
    _Float16*    __restrict__ part)
{
    const int tid  = threadIdx.x;
    const int lane = tid & 63;
    const int wid  = tid >> 6;
    const int wr   = wid >> 1;
    const int wc   = wid & 1;
    const int bid  = blockIdx.x;
    const int ks   = bid & (KSPL - 1);
    const int mt   = bid >> 4;
    const int m0   = mt * BM;

    __shared__ short As[CHUNK];      // 16 KB single buffer (x, unscaled)
    __shared__ short Bs[3][CHUNK];   // 48 KB, Wf^T

    // --- prologue: per-lane packed zw for its 4 rows x 4 li ---
    f16x2 zwp[4][4];
    #pragma unroll
    for (int m = 0; m < 4; ++m) {
        int row = wr * 64 + m * 16 + (lane & 15);
        int b   = m0 + row;
        int g   = gid[b];
        float4 mu = *reinterpret_cast<const float4*>(&zw_mu[g * LW_SZ + ks * 4]);
        float4 sg = *reinterpret_cast<const float4*>(&zw_sigma[g * LW_SZ + ks * 4]);
        float4 ep = *reinterpret_cast<const float4*>(&eps_w[b * LW_SZ + ks * 4]);
        float v0 = mu.x + softplus_f(sg.x) * ep.x;
        float v1 = mu.y + softplus_f(sg.y) * ep.y;
        float v2 = mu.z + softplus_f(sg.z) * ep.z;
        float v3 = mu.w + softplus_f(sg.w) * ep.w;
        _Float16 h0 = (_Float16)v0, h1 = (_Float16)v1, h2 = (_Float16)v2, h3 = (_Float16)v3;
        zwp[m][0] = (f16x2){h0, h0};
        zwp[m][1] = (f16x2){h1, h1};
        zwp[m][2] = (f16x2){h2, h2};
        zwp[m][3] = (f16x2){h3, h3};
    }

    const int soff = wid * 2048 + lane * 8;    // per-thread staging offset (shorts)
    const int doff = wid * 2048;

    // prologue issues, FIFO order: B[0], A[0], B[1]
    {
        const short* sB0 = wfT + (ks * 16 + 0) * CHUNK;            // tile(s=0)
        const short* sA0 = xh + (mt * 4 + 0) * CHUNK;
        const short* sB1 = wfT + (ks * 16 + 4) * CHUNK;            // tile(s=1)
        #pragma unroll
        for (int j = 0; j < 4; ++j)
            __builtin_amdgcn_global_load_lds((gas_ptr)(sB0 + soff + j * 512),
                                             (las_ptr)(&Bs[0][doff + j * 512]), 16, 0, 0);
        #pragma unroll
        for (int j = 0; j < 4; ++j)
            __builtin_amdgcn_global_load_lds((gas_ptr)(sA0 + soff + j * 512),
                                             (las_ptr)(&As[doff + j * 512]), 16, 0, 0);
        #pragma unroll
        for (int j = 0; j < 4; ++j)
            __builtin_amdgcn_global_load_lds((gas_ptr)(sB1 + soff + j * 512),
                                             (las_ptr)(&Bs[1][doff + j * 512]), 16, 0, 0);
    }
    asm volatile("s_waitcnt vmcnt(4)" ::: "memory");   // B[0]+A[0] landed
    __builtin_amdgcn_s_barrier();

    f32x4 acc[4][4];
    #pragma unroll
    for (int m = 0; m < 4; ++m)
        #pragma unroll
        for (int n = 0; n < 4; ++n)
            acc[m][n] = (f32x4){0.f, 0.f, 0.f, 0.f};

    for (int c = 0; c < 4; ++c) {
        union { f16x8 v8; f16x2 v2[4]; } areg[2][4];   // [kb][m], held across li

        #pragma unroll
        for (int li = 0; li < 4; ++li) {
            const int s = c * 4 + li;

            // --- issue B[s+2] (Bs[(s+2)%3]; that buffer's last read was step s-1) ---
            if (s + 2 < NSTEP) {
                const int s2 = s + 2;
                const short* sB = wfT + (ks * 16 + (s2 & 3) * 4 + (s2 >> 2)) * CHUNK;
                short* dB = &Bs[s2 % 3][doff];
                #pragma unroll
                for (int j = 0; j < 4; ++j)
                    __builtin_amdgcn_global_load_lds((gas_ptr)(sB + soff + j * 512),
                                                     (las_ptr)(dB + j * 512), 16, 0, 0);
            }
            // --- issue A[c+1] at li==1 (As free after li==0's barrier) ---
            if (li == 1 && c < 3) {
                const short* sA = xh + (mt * 4 + c + 1) * CHUNK;
                #pragma unroll
                for (int j = 0; j < 4; ++j)
                    __builtin_amdgcn_global_load_lds((gas_ptr)(sA + soff + j * 512),
                                                     (las_ptr)(&As[doff + j * 512]), 16, 0, 0);
            }
            __builtin_amdgcn_sched_barrier(0);   // keep stage-issue ahead of compute

            // --- li==0: pull A-fragments into registers (reused for all li) ---
            if (li == 0) {
                #pragma unroll
                for (int kb = 0; kb < 2; ++kb)
                    #pragma unroll
                    for (int m = 0; m < 4; ++m) {
                        int row = wr * 64 + m * 16 + (lane & 15);
                        int si = (row * BK + kb * 32 + (lane >> 4) * 8) ^ ((row & 7) << 3);
                        areg[kb][m].v8 = *reinterpret_cast<const f16x8*>(&As[si]);
                    }
            }

            const short* Bb = Bs[s % 3];
            __builtin_amdgcn_s_setprio(1);
            #pragma unroll
            for (int kb = 0; kb < 2; ++kb) {
                union { f16x8 v8; f16x2 v2[4]; } bfv[4], as_[4];
                #pragma unroll
                for (int n = 0; n < 4; ++n) {
                    int rowu = wc * 64 + n * 16 + (lane & 15);
                    int si = (rowu * BK + kb * 32 + (lane >> 4) * 8) ^ ((rowu & 7) << 3);
                    bfv[n].v8 = *reinterpret_cast<const f16x8*>(&Bb[si]);
                }
                #pragma unroll
                for (int m = 0; m < 4; ++m) {
                    #pragma unroll
                    for (int w = 0; w < 4; ++w)
                        as_[m].v2[w] = areg[kb][m].v2[w] * zwp[m][li];   // v_pk_mul_f16
                }
                #pragma unroll
                for (int m = 0; m < 4; ++m)
                    #pragma unroll
                    for (int n = 0; n < 4; ++n)
                        acc[m][n] = __builtin_amdgcn_mfma_f32_16x16x32_f16(
                            as_[m].v8, bfv[n].v8, acc[m][n], 0, 0, 0);
            }
            __builtin_amdgcn_s_setprio(0);

            // --- end-of-step: counted waits (FIFO-derived), lgkmcnt(0) so
            //     our LDS reads retire before others overwrite the buffer ---
            if (li == 0) {
                asm volatile("s_waitcnt vmcnt(4) lgkmcnt(0)" ::: "memory");
                __builtin_amdgcn_s_barrier();
            } else if (li == 1) {
                if (c < 3) { asm volatile("s_waitcnt vmcnt(8) lgkmcnt(0)" ::: "memory"); }
                else       { asm volatile("s_waitcnt vmcnt(4) lgkmcnt(0)" ::: "memory"); }
                __builtin_amdgcn_s_barrier();
            } else if (li == 2) {
                if (c < 3) { asm volatile("s_waitcnt vmcnt(8) lgkmcnt(0)" ::: "memory"); }
                else       { asm volatile("s_waitcnt vmcnt(0) lgkmcnt(0)" ::: "memory"); }
                __builtin_amdgcn_s_barrier();
            } else {  // li == 3
                if (s != NSTEP - 1) {
                    asm volatile("s_waitcnt vmcnt(4) lgkmcnt(0)" ::: "memory");
                    __builtin_amdgcn_s_barrier();
                }
            }
        }
    }

    // --- epilogue: f16 partials, slice ks, NON-TEMPORAL (bypass L2) ---
    _Float16* dst = part + (size_t)ks * (B_SZ * U_SZ);
    #pragma unroll
    for (int m = 0; m < 4; ++m) {
        int row0 = m0 + wr * 64 + m * 16 + ((lane >> 4) << 2);
        #pragma unroll
        for (int n = 0; n < 4; ++n) {
            int col = wc * 64 + n * 16 + (lane & 15);
            #pragma unroll
            for (int j = 0; j < 4; ++j)
                __builtin_nontemporal_store((_Float16)acc[m][n][j],
                                            &dst[(row0 + j) * U_SZ + col]);
        }
    }
}

// ---------------------------------------------------------------------------
// Reduce + bias: out[b,u] = sum_ks part[ks][b][u] + bias[b,u].
// 8 outputs/thread, f16x8 non-temporal partial loads. Overwrites d_out fully.
// ---------------------------------------------------------------------------
__global__ __launch_bounds__(256) void fmd_reduce3(
    const _Float16* __restrict__ part,
    const float* __restrict__ eps_b,
    const float* __restrict__ zb_mu,
    const float* __restrict__ zb_sigma,
    const float* __restrict__ Bf,
    const int*   __restrict__ gid,
    float*       __restrict__ out)
{
    const int tid = threadIdx.x;
    const int bid = blockIdx.x;               // 256 blocks
    const int i8  = bid * 256 + tid;          // 8-elem unit index (65536 total)
    const int r   = tid >> 4;                 // local b row 0..15
    const int u0  = (tid & 15) * 8;           // u start

    __shared__ float zb[16][33];
    {
        int e = tid;                          // 2 entries per thread (512 total)
        int rr = e >> 5, cc = e & 31;
        int b2 = bid * 16 + rr;
        int g  = gid[b2];
        zb[rr][cc] = zb_mu[g * LB_SZ + cc]
                   + softplus_f(zb_sigma[g * LB_SZ + cc]) * eps_b[b2 * LB_SZ + cc];
        e += 256; rr = e >> 5; cc = e & 31;
        b2 = bid * 16 + rr;
        g  = gid[b2];
        zb[rr][cc] = zb_mu[g * LB_SZ + cc]
                   + softplus_f(zb_sigma[g * LB_SZ + cc]) * eps_b[b2 * LB_SZ + cc];
    }
    __syncthreads();

    f32x4 a0 = (f32x4){0.f, 0.f, 0.f, 0.f};
    f32x4 a1 = (f32x4){0.f, 0.f, 0.f, 0.f};
    #pragma unroll
    for (int l = 0; l < LB_SZ; ++l) {
        float z = zb[r][l];
        f32x4 b0 = *reinterpret_cast<const f32x4*>(&Bf[l * U_SZ + u0]);
        f32x4 b1 = *reinterpret_cast<const f32x4*>(&Bf[l * U_SZ + u0 + 4]);
        a0 += z * b0;
        a1 += z * b1;
    }

    #pragma unroll
    for (int ks = 0; ks < KSPL; ++ks) {
        f16x8 p = __builtin_nontemporal_load(
            reinterpret_cast<const f16x8*>(&part[(size_t)ks * (B_SZ * U_SZ) + (size_t)i8 * 8]));
        a0[0] += (float)p[0]; a0[1] += (float)p[1];
        a0[2] += (float)p[2]; a0[3] += (float)p[3];
        a1[0] += (float)p[4]; a1[1] += (float)p[5];
        a1[2] += (float)p[6]; a1[3] += (float)p[7];
    }
    *reinterpret_cast<f32x4*>(&out[(size_t)i8 * 8])     = a0;
    *reinterpret_cast<f32x4*>(&out[(size_t)i8 * 8 + 4]) = a1;
}

// ---------------------------------------------------------------------------
// Legacy fallback (no workspace): bias + atomic GEMM (bf16)
// ---------------------------------------------------------------------------
__global__ __launch_bounds__(256) void fmd_bias(
    const float* __restrict__ eps_b,
    const float* __restrict__ zb_mu,
    const float* __restrict__ zb_sigma,
    const float* __restrict__ Bf,
    const int*   __restrict__ gid,
    float*       __restrict__ out)
{
    const int half = threadIdx.x >> 7;
    const int u    = threadIdx.x & 127;
    const int b    = blockIdx.x * 2 + half;

    __shared__ float zb[2][LB_SZ];
    if (u < LB_SZ) {
        int g = gid[b];
        float sg = softplus_f(zb_sigma[g * LB_SZ + u]);
        zb[half][u] = zb_mu[g * LB_SZ + u] + sg * eps_b[b * LB_SZ + u];
    }
    __syncthreads();

    float acc = 0.0f;
    #pragma unroll
    for (int l = 0; l < LB_SZ; ++l)
        acc += zb[half][l] * Bf[l * U_SZ + u];
    out[b * U_SZ + u] = acc;
}

__global__ __launch_bounds__(256, 2) void fmd_gemm_legacy(
    const float* __restrict__ x,
    const float* __restrict__ eps_w,
    const float* __restrict__ zw_mu,
    const float* __restrict__ zw_sigma,
    const float* __restrict__ Wf,
    const int*   __restrict__ gid,
    float*       __restrict__ out)
{
    const int tid  = threadIdx.x;
    const int lane = tid & 63;
    const int wid  = tid >> 6;
    const int wr   = wid >> 1;
    const int wc   = wid & 1;
    const int bid  = blockIdx.x;
    const int ks   = bid & (KSPL - 1);
    const int mt   = bid >> 4;
    const int m0   = mt * BM;

    __shared__ short As[BM * BK];
    __shared__ short Bs[U_SZ * BK];
    __shared__ float zw_s[BM][4];

    for (int it = tid; it < BM * 4; it += 256) {
        int r = it >> 2, lloc = it & 3;
        int b = m0 + r;
        int g = gid[b];
        int l = ks * 4 + lloc;
        float sg = softplus_f(zw_sigma[g * LW_SZ + l]);
        zw_s[r][lloc] = zw_mu[g * LW_SZ + l] + sg * eps_w[b * LW_SZ + l];
    }

    f32x4 acc[4][4];
    #pragma unroll
    for (int m = 0; m < 4; ++m)
        #pragma unroll
        for (int n = 0; n < 4; ++n)
            acc[m][n] = (f32x4){0.f, 0.f, 0.f, 0.f};

    for (int s = 0; s < NSTEP; ++s) {
        __syncthreads();
        const int li = s >> 2;
        const int i0 = (s & 3) * BK;
        const int k0 = ks * (K_SZ / KSPL) + s * BK;

        #pragma unroll
        for (int it = 0; it < 8; ++it) {
            int idx = it * 256 + tid;
            int r = idx >> 4, c4 = idx & 15;
            float4 xv = *reinterpret_cast<const float4*>(&x[(m0 + r) * IN_SZ + i0 + c4 * 4]);
            float zw = zw_s[r][li];
            ushort h0 = f2bf(xv.x * zw), h1 = f2bf(xv.y * zw);
            ushort h2 = f2bf(xv.z * zw), h3 = f2bf(xv.w * zw);
            unsigned long long pw = (unsigned long long)h0
                                  | ((unsigned long long)h1 << 16)
                                  | ((unsigned long long)h2 << 32)
                                  | ((unsigned long long)h3 << 48);
            int si = (r * BK + c4 * 4) ^ ((r & 7) << 3);
            *reinterpret_cast<unsigned long long*>(&As[si]) = pw;
        }
        #pragma unroll
        for (int it = 0; it < 4; ++it) {
            int idx = it * 256 + tid;
            int u = idx & 127, kg = idx >> 7;
            union { ushort h[8]; bf16x8 v; } pk;
            #pragma unroll
            for (int j = 0; j < 8; ++j)
                pk.h[j] = f2bf(Wf[(k0 + kg * 8 + j) * U_SZ + u]);
            int si = (u * BK + kg * 8) ^ ((u & 7) << 3);
            *reinterpret_cast<bf16x8*>(&Bs[si]) = pk.v;
        }
        __syncthreads();

        #pragma unroll
        for (int kb = 0; kb < 2; ++kb) {
            bf16x8 af[4], bfr[4];
            #pragma unroll
            for (int m = 0; m < 4; ++m) {
                int row = wr * 64 + m * 16 + (lane & 15);
                int si = (row * BK + kb * 32 + (lane >> 4) * 8) ^ ((row & 7) << 3);
                af[m] = *reinterpret_cast<const bf16x8*>(&As[si]);
            }
            #pragma unroll
            for (int n = 0; n < 4; ++n) {
                int rowu = wc * 64 + n * 16 + (lane & 15);
                int si = (rowu * BK + kb * 32 + (lane >> 4) * 8) ^ ((rowu & 7) << 3);
                bfr[n] = *reinterpret_cast<const bf16x8*>(&Bs[si]);
            }
            #pragma unroll
            for (int m = 0; m < 4; ++m)
                #pragma unroll
                for (int n = 0; n < 4; ++n)
                    acc[m][n] = __builtin_amdgcn_mfma_f32_16x16x32_bf16(af[m], bfr[n], acc[m][n], 0, 0, 0);
        }
    }

    #pragma unroll
    for (int m = 0; m < 4; ++m) {
        int row0 = m0 + wr * 64 + m * 16 + ((lane >> 4) << 2);
        #pragma unroll
        for (int n = 0; n < 4; ++n) {
            int col = wc * 64 + n * 16 + (lane & 15);
            #pragma unroll
            for (int j = 0; j < 4; ++j)
                atomicAdd(&out[(row0 + j) * U_SZ + col], acc[m][n][j]);
        }
    }
}

extern "C" void kernel_launch(void* const* d_in, const int* in_sizes, int n_in,
                              void* d_out, int out_size, void* d_ws, size_t ws_size,
                              hipStream_t stream) {
    const float* x        = (const float*)d_in[0];
    const float* eps_w    = (const float*)d_in[1];
    const float* eps_b    = (const float*)d_in[2];
    const float* zw_mu    = (const float*)d_in[3];
    const float* zw_sigma = (const float*)d_in[4];
    const float* Wf       = (const float*)d_in[5];
    const float* zb_mu    = (const float*)d_in[6];
    const float* zb_sigma = (const float*)d_in[7];
    const float* Bf       = (const float*)d_in[8];
    const int*   gid      = (const int*)d_in[9];
    float* out = (float*)d_out;

    const size_t WFT_BYTES  = (size_t)K_SZ * U_SZ * 2;            // 4 MB
    const size_t XH_OFF     = WFT_BYTES;
    const size_t XH_BYTES   = (size_t)B_SZ * IN_SZ * 2;           // 2 MB
    const size_t PART_OFF   = XH_OFF + XH_BYTES;
    const size_t PART_BYTES = (size_t)KSPL * B_SZ * U_SZ * 2;     // 16 MB

    if (ws_size >= PART_OFF + PART_BYTES) {
        short*     wfT  = (short*)d_ws;
        short*     xh   = (short*)((char*)d_ws + XH_OFF);
        _Float16*  part = (_Float16*)((char*)d_ws + PART_OFF);
        fmd_prep<<<NTILE + (B_SZ / BM) * 4, 256, 0, stream>>>(Wf, x, wfT, xh);
        fmd_gemm5<<<(B_SZ / BM) * KSPL, 256, 0, stream>>>(
            xh, wfT, zw_mu, zw_sigma, eps_w, gid, part);
        fmd_reduce3<<<(B_SZ * U_SZ) / 2048, 256, 0, stream>>>(
            part, eps_b, zb_mu, zb_sigma, Bf, gid, out);
    } else {
        fmd_bias<<<B_SZ / 2, 256, 0, stream>>>(eps_b, zb_mu, zb_sigma, Bf, gid, out);
        fmd_gemm_legacy<<<(B_SZ / BM) * KSPL, 256, 0, stream>>>(
            x, eps_w, zw_mu, zw_sigma, Wf, gid, out);
    }
}

// Round 6
// 43.807 us; speedup vs baseline: 1.1149x; 1.1149x over previous
//
#include <hip/hip_runtime.h>
#include <hip/hip_bf16.h>
#include <stdint.h>

// Problem constants
#define B_SZ   4096
#define IN_SZ  256
#define U_SZ   128
#define G_SZ   1000
#define LW_SZ  64
#define LB_SZ  32
#define K_SZ   (LW_SZ * IN_SZ)      // 16384

// GEMM: out[B, U] = A[B, K] * Wf[K, U];  A[b, l*256+i] = zw[b,l] * x[b,i]
// LDS-FREE design: prep emits both operands in exact MFMA fragment order;
// gemm loads fragments global->register, fully coalesced, no barriers.
#define BM     128
#define KSPL   16                   // split over l: 4 l's per block
#define NSTEP  16                   // s = c*4 + li  (c: x-chunk, li: local l)
#define NTILE  (K_SZ / 64)          // 256 k-tiles of 64
#define TSH    8192                 // shorts per tile (64k x 128u or 128r x 64k)

typedef __attribute__((ext_vector_type(8))) short  bf16x8;
typedef __attribute__((ext_vector_type(4))) float  f32x4;
typedef __attribute__((ext_vector_type(8))) _Float16 f16x8;
typedef __attribute__((ext_vector_type(2))) _Float16 f16x2;

__device__ __forceinline__ ushort f2bf(float f) {
    unsigned u = __float_as_uint(f);
    u += 0x7fffu + ((u >> 16) & 1u);
    return (ushort)(u >> 16);
}

__device__ __forceinline__ float softplus_f(float v) {
    return fmaxf(v, 0.0f) + log1pf(__expf(-fabsf(v)));
}

__device__ __forceinline__ f16x8 mulzw(f16x8 a, f16x2 z) {
    union { f16x8 v8; f16x2 v2[4]; } in, out;
    in.v8 = a;
    #pragma unroll
    for (int w = 0; w < 4; ++w) out.v2[w] = in.v2[w] * z;   // v_pk_mul_f16
    return out.v8;
}

// ---------------------------------------------------------------------------
// Prep: fragment-order layouts.
// wfT tile t (k rows t*64..+63, all 128 u), 8192 shorts:
//   wfT[t*8192 + (kb*8 + u16)*512 + l*8 + j] = f16(Wf[(t*64 + kb*32 + (l>>4)*8 + j)*128 + u16*16 + (l&15)])
// xh chunk (mt,c) (rows mt*128..+127, cols c*64..+63), 8192 shorts:
//   xh[(mt*4+c)*8192 + ((wr*4+m)*2+kb)*512 + l*8 + j]
//       = f16(x[(mt*128 + wr*64 + m*16 + (l&15))*256 + c*64 + kb*32 + (l>>4)*8 + j])
// ---------------------------------------------------------------------------
__global__ __launch_bounds__(256) void fmd_prep(
    const float* __restrict__ Wf, const float* __restrict__ x,
    short* __restrict__ wfT, short* __restrict__ xh)
{
    const int tid = threadIdx.x;
    if (blockIdx.x < NTILE) {
        const int t = blockIdx.x;               // k-tile 0..255
        __shared__ float lds[64 * 133];         // [kk][u], pad 133 (2-way max)
        #pragma unroll
        for (int it = 0; it < 8; ++it) {
            int idx = it * 256 + tid;           // 2048 float4 slots
            int kk = idx >> 5, u4 = idx & 31;
            float4 v = *reinterpret_cast<const float4*>(&Wf[(t * 64 + kk) * U_SZ + u4 * 4]);
            *reinterpret_cast<float4*>(&lds[kk * 133 + u4 * 4]) = v;
        }
        __syncthreads();
        short* tile = wfT + t * TSH;
        #pragma unroll
        for (int it = 0; it < 4; ++it) {
            int p = it * 256 + tid;             // 0..1023 f16x8 slots
            int kb  = p >> 9;
            int u16 = (p >> 6) & 7;
            int l   = p & 63;
            int u   = u16 * 16 + (l & 15);
            int kk0 = kb * 32 + (l >> 4) * 8;
            union { _Float16 h[8]; f16x8 v; } pk;
            #pragma unroll
            for (int j = 0; j < 8; ++j)
                pk.h[j] = (_Float16)lds[(kk0 + j) * 133 + u];
            *reinterpret_cast<f16x8*>(&tile[p * 8]) = pk.v;
        }
    } else {
        const int bb = blockIdx.x - NTILE;      // 0..127 : (mtile, chunk)
        const int mt = bb >> 2, c = bb & 3;
        short* tile = xh + bb * TSH;
        #pragma unroll
        for (int it = 0; it < 4; ++it) {
            int p = it * 256 + tid;             // 0..1023 f16x8 slots
            int frag = p >> 6;                  // (wr*4+m)*2+kb
            int l    = p & 63;
            int wr2  = frag >> 3;
            int m2   = (frag >> 1) & 3;
            int kb   = frag & 1;
            int row  = mt * 128 + wr2 * 64 + m2 * 16 + (l & 15);
            int col  = c * 64 + kb * 32 + (l >> 4) * 8;
            const float* src = &x[row * IN_SZ + col];
            float4 a = *reinterpret_cast<const float4*>(src);
            float4 b = *reinterpret_cast<const float4*>(src + 4);
            union { _Float16 h[8]; f16x8 v; } pk;
            pk.h[0] = (_Float16)a.x; pk.h[1] = (_Float16)a.y;
            pk.h[2] = (_Float16)a.z; pk.h[3] = (_Float16)a.w;
            pk.h[4] = (_Float16)b.x; pk.h[5] = (_Float16)b.y;
            pk.h[6] = (_Float16)b.z; pk.h[7] = (_Float16)b.w;
            *reinterpret_cast<f16x8*>(&tile[p * 8]) = pk.v;
        }
    }
}

// ---------------------------------------------------------------------------
// GEMM v6 (LDS-free): 512 blocks (32 mt x 16 ks), 4 waves, 64x64 wave tile.
// Fragments loaded global->register, coalesced dwordx4; double-buffered
// (breg[s&1], areg[c&1]); prefetch next step during MFMA. No barriers, no
// LDS -- waves fully independent; compiler handles vmcnt for reg loads.
// zw applied per-li via v_pk_mul_f16 on the A fragment.
// ---------------------------------------------------------------------------
__global__ __launch_bounds__(256, 2) void fmd_gemm6(
    const short* __restrict__ xh,
    const short* __restrict__ wfT,
    const float* __restrict__ zw_mu,
    const float* __restrict__ zw_sigma,
    const float* __restrict__ eps_w,
    const int*   __restrict__ gid,
    _Float16*    __restrict__ part)
{
    const int tid  = threadIdx.x;
    const int lane = tid & 63;
    const int wid  = tid >> 6;
    const int wr   = wid >> 1;
    const int wc   = wid & 1;
    const int bid  = blockIdx.x;
    const int ks   = bid & (KSPL - 1);
    const int mt   = bid >> 4;
    const int m0   = mt * BM;
    const int lane8 = lane * 8;

    // --- per-lane packed zw for its 4 rows x 4 li ---
    f16x2 zwp[4][4];
    #pragma unroll
    for (int m = 0; m < 4; ++m) {
        int row = wr * 64 + m * 16 + (lane & 15);
        int b   = m0 + row;
        int g   = gid[b];
        float4 mu = *reinterpret_cast<const float4*>(&zw_mu[g * LW_SZ + ks * 4]);
        float4 sg = *reinterpret_cast<const float4*>(&zw_sigma[g * LW_SZ + ks * 4]);
        float4 ep = *reinterpret_cast<const float4*>(&eps_w[b * LW_SZ + ks * 4]);
        float v0 = mu.x + softplus_f(sg.x) * ep.x;
        float v1 = mu.y + softplus_f(sg.y) * ep.y;
        float v2 = mu.z + softplus_f(sg.z) * ep.z;
        float v3 = mu.w + softplus_f(sg.w) * ep.w;
        _Float16 h0 = (_Float16)v0, h1 = (_Float16)v1, h2 = (_Float16)v2, h3 = (_Float16)v3;
        zwp[m][0] = (f16x2){h0, h0};
        zwp[m][1] = (f16x2){h1, h1};
        zwp[m][2] = (f16x2){h2, h2};
        zwp[m][3] = (f16x2){h3, h3};
    }

    f16x8 areg[2][2][4];   // [c&1][kb][m]
    f16x8 breg[2][2][4];   // [s&1][kb][n]

    // prologue: A(c=0), B(s=0)
    {
        const short* ap = xh + (mt * 4 + 0) * TSH;
        #pragma unroll
        for (int kb = 0; kb < 2; ++kb)
            #pragma unroll
            for (int m = 0; m < 4; ++m)
                areg[0][kb][m] = *reinterpret_cast<const f16x8*>(
                    &ap[((wr * 4 + m) * 2 + kb) * 512 + lane8]);
        const int t0 = (ks * 4 + 0) * 4 + 0;
        const short* bp = wfT + t0 * TSH;
        #pragma unroll
        for (int kb = 0; kb < 2; ++kb)
            #pragma unroll
            for (int n = 0; n < 4; ++n)
                breg[0][kb][n] = *reinterpret_cast<const f16x8*>(
                    &bp[(kb * 8 + wc * 4 + n) * 512 + lane8]);
    }

    f32x4 acc[4][4];
    #pragma unroll
    for (int m = 0; m < 4; ++m)
        #pragma unroll
        for (int n = 0; n < 4; ++n)
            acc[m][n] = (f32x4){0.f, 0.f, 0.f, 0.f};

    #pragma unroll
    for (int c = 0; c < 4; ++c) {
        #pragma unroll
        for (int li = 0; li < 4; ++li) {
            const int s = c * 4 + li;

            // --- prefetch B(s+1) ---
            if (s + 1 < NSTEP) {
                const int sn = s + 1;
                const int t  = (ks * 4 + (sn & 3)) * 4 + (sn >> 2);
                const short* bp = wfT + t * TSH;
                #pragma unroll
                for (int kb = 0; kb < 2; ++kb)
                    #pragma unroll
                    for (int n = 0; n < 4; ++n)
                        breg[sn & 1][kb][n] = *reinterpret_cast<const f16x8*>(
                            &bp[(kb * 8 + wc * 4 + n) * 512 + lane8]);
            }
            // --- prefetch A(c+1) mid-chunk ---
            if (li == 2 && c < 3) {
                const short* ap = xh + (mt * 4 + c + 1) * TSH;
                #pragma unroll
                for (int kb = 0; kb < 2; ++kb)
                    #pragma unroll
                    for (int m = 0; m < 4; ++m)
                        areg[(c + 1) & 1][kb][m] = *reinterpret_cast<const f16x8*>(
                            &ap[((wr * 4 + m) * 2 + kb) * 512 + lane8]);
            }

            // --- compute step s ---
            #pragma unroll
            for (int kb = 0; kb < 2; ++kb) {
                f16x8 as_[4];
                #pragma unroll
                for (int m = 0; m < 4; ++m)
                    as_[m] = mulzw(areg[c & 1][kb][m], zwp[m][li]);
                #pragma unroll
                for (int m = 0; m < 4; ++m)
                    #pragma unroll
                    for (int n = 0; n < 4; ++n)
                        acc[m][n] = __builtin_amdgcn_mfma_f32_16x16x32_f16(
                            as_[m], breg[s & 1][kb][n], acc[m][n], 0, 0, 0);
            }
        }
    }

    // --- epilogue: f16 partials, slice ks (plain stores; L2-friendly) ---
    _Float16* dst = part + (size_t)ks * (B_SZ * U_SZ);
    #pragma unroll
    for (int m = 0; m < 4; ++m) {
        int row0 = m0 + wr * 64 + m * 16 + ((lane >> 4) << 2);
        #pragma unroll
        for (int n = 0; n < 4; ++n) {
            int col = wc * 64 + n * 16 + (lane & 15);
            #pragma unroll
            for (int j = 0; j < 4; ++j)
                dst[(row0 + j) * U_SZ + col] = (_Float16)acc[m][n][j];
        }
    }
}

// ---------------------------------------------------------------------------
// Reduce + bias: out[b,u] = sum_ks part[ks][b][u] + bias[b,u].
// 8 outputs/thread, plain (cache-friendly) loads. Overwrites d_out fully.
// ---------------------------------------------------------------------------
__global__ __launch_bounds__(256) void fmd_reduce4(
    const _Float16* __restrict__ part,
    const float* __restrict__ eps_b,
    const float* __restrict__ zb_mu,
    const float* __restrict__ zb_sigma,
    const float* __restrict__ Bf,
    const int*   __restrict__ gid,
    float*       __restrict__ out)
{
    const int tid = threadIdx.x;
    const int bid = blockIdx.x;               // 256 blocks
    const int i8  = bid * 256 + tid;          // 8-elem unit index (65536 total)
    const int r   = tid >> 4;                 // local b row 0..15
    const int u0  = (tid & 15) * 8;           // u start

    __shared__ float zb[16][33];
    {
        int e = tid;                          // 2 entries per thread (512 total)
        int rr = e >> 5, cc = e & 31;
        int b2 = bid * 16 + rr;
        int g  = gid[b2];
        zb[rr][cc] = zb_mu[g * LB_SZ + cc]
                   + softplus_f(zb_sigma[g * LB_SZ + cc]) * eps_b[b2 * LB_SZ + cc];
        e += 256; rr = e >> 5; cc = e & 31;
        b2 = bid * 16 + rr;
        g  = gid[b2];
        zb[rr][cc] = zb_mu[g * LB_SZ + cc]
                   + softplus_f(zb_sigma[g * LB_SZ + cc]) * eps_b[b2 * LB_SZ + cc];
    }
    __syncthreads();

    f32x4 a0 = (f32x4){0.f, 0.f, 0.f, 0.f};
    f32x4 a1 = (f32x4){0.f, 0.f, 0.f, 0.f};
    #pragma unroll
    for (int l = 0; l < LB_SZ; ++l) {
        float z = zb[r][l];
        f32x4 b0 = *reinterpret_cast<const f32x4*>(&Bf[l * U_SZ + u0]);
        f32x4 b1 = *reinterpret_cast<const f32x4*>(&Bf[l * U_SZ + u0 + 4]);
        a0 += z * b0;
        a1 += z * b1;
    }

    #pragma unroll
    for (int ks = 0; ks < KSPL; ++ks) {
        f16x8 p = *reinterpret_cast<const f16x8*>(
            &part[(size_t)ks * (B_SZ * U_SZ) + (size_t)i8 * 8]);
        a0[0] += (float)p[0]; a0[1] += (float)p[1];
        a0[2] += (float)p[2]; a0[3] += (float)p[3];
        a1[0] += (float)p[4]; a1[1] += (float)p[5];
        a1[2] += (float)p[6]; a1[3] += (float)p[7];
    }
    *reinterpret_cast<f32x4*>(&out[(size_t)i8 * 8])     = a0;
    *reinterpret_cast<f32x4*>(&out[(size_t)i8 * 8 + 4]) = a1;
}

// ---------------------------------------------------------------------------
// Legacy fallback (no workspace): bias + atomic GEMM (bf16)
// ---------------------------------------------------------------------------
__global__ __launch_bounds__(256) void fmd_bias(
    const float* __restrict__ eps_b,
    const float* __restrict__ zb_mu,
    const float* __restrict__ zb_sigma,
    const float* __restrict__ Bf,
    const int*   __restrict__ gid,
    float*       __restrict__ out)
{
    const int half = threadIdx.x >> 7;
    const int u    = threadIdx.x & 127;
    const int b    = blockIdx.x * 2 + half;

    __shared__ float zb[2][LB_SZ];
    if (u < LB_SZ) {
        int g = gid[b];
        float sg = softplus_f(zb_sigma[g * LB_SZ + u]);
        zb[half][u] = zb_mu[g * LB_SZ + u] + sg * eps_b[b * LB_SZ + u];
    }
    __syncthreads();

    float acc = 0.0f;
    #pragma unroll
    for (int l = 0; l < LB_SZ; ++l)
        acc += zb[half][l] * Bf[l * U_SZ + u];
    out[b * U_SZ + u] = acc;
}

__global__ __launch_bounds__(256, 2) void fmd_gemm_legacy(
    const float* __restrict__ x,
    const float* __restrict__ eps_w,
    const float* __restrict__ zw_mu,
    const float* __restrict__ zw_sigma,
    const float* __restrict__ Wf,
    const int*   __restrict__ gid,
    float*       __restrict__ out)
{
    const int tid  = threadIdx.x;
    const int lane = tid & 63;
    const int wid  = tid >> 6;
    const int wr   = wid >> 1;
    const int wc   = wid & 1;
    const int bid  = blockIdx.x;
    const int ks   = bid & (KSPL - 1);
    const int mt   = bid >> 4;
    const int m0   = mt * BM;

    __shared__ short As[BM * 64];
    __shared__ short Bs[U_SZ * 64];
    __shared__ float zw_s[BM][4];

    for (int it = tid; it < BM * 4; it += 256) {
        int r = it >> 2, lloc = it & 3;
        int b = m0 + r;
        int g = gid[b];
        int l = ks * 4 + lloc;
        float sg = softplus_f(zw_sigma[g * LW_SZ + l]);
        zw_s[r][lloc] = zw_mu[g * LW_SZ + l] + sg * eps_w[b * LW_SZ + l];
    }

    f32x4 acc[4][4];
    #pragma unroll
    for (int m = 0; m < 4; ++m)
        #pragma unroll
        for (int n = 0; n < 4; ++n)
            acc[m][n] = (f32x4){0.f, 0.f, 0.f, 0.f};

    for (int s = 0; s < NSTEP; ++s) {
        __syncthreads();
        const int li = s >> 2;
        const int i0 = (s & 3) * 64;
        const int k0 = ks * (K_SZ / KSPL) + s * 64;

        #pragma unroll
        for (int it = 0; it < 8; ++it) {
            int idx = it * 256 + tid;
            int r = idx >> 4, c4 = idx & 15;
            float4 xv = *reinterpret_cast<const float4*>(&x[(m0 + r) * IN_SZ + i0 + c4 * 4]);
            float zw = zw_s[r][li];
            ushort h0 = f2bf(xv.x * zw), h1 = f2bf(xv.y * zw);
            ushort h2 = f2bf(xv.z * zw), h3 = f2bf(xv.w * zw);
            unsigned long long pw = (unsigned long long)h0
                                  | ((unsigned long long)h1 << 16)
                                  | ((unsigned long long)h2 << 32)
                                  | ((unsigned long long)h3 << 48);
            int si = (r * 64 + c4 * 4) ^ ((r & 7) << 3);
            *reinterpret_cast<unsigned long long*>(&As[si]) = pw;
        }
        #pragma unroll
        for (int it = 0; it < 4; ++it) {
            int idx = it * 256 + tid;
            int u = idx & 127, kg = idx >> 7;
            union { ushort h[8]; bf16x8 v; } pk;
            #pragma unroll
            for (int j = 0; j < 8; ++j)
                pk.h[j] = f2bf(Wf[(k0 + kg * 8 + j) * U_SZ + u]);
            int si = (u * 64 + kg * 8) ^ ((u & 7) << 3);
            *reinterpret_cast<bf16x8*>(&Bs[si]) = pk.v;
        }
        __syncthreads();

        #pragma unroll
        for (int kb = 0; kb < 2; ++kb) {
            bf16x8 af[4], bfr[4];
            #pragma unroll
            for (int m = 0; m < 4; ++m) {
                int row = wr * 64 + m * 16 + (lane & 15);
                int si = (row * 64 + kb * 32 + (lane >> 4) * 8) ^ ((row & 7) << 3);
                af[m] = *reinterpret_cast<const bf16x8*>(&As[si]);
            }
            #pragma unroll
            for (int n = 0; n < 4; ++n) {
                int rowu = wc * 64 + n * 16 + (lane & 15);
                int si = (rowu * 64 + kb * 32 + (lane >> 4) * 8) ^ ((rowu & 7) << 3);
                bfr[n] = *reinterpret_cast<const bf16x8*>(&Bs[si]);
            }
            #pragma unroll
            for (int m = 0; m < 4; ++m)
                #pragma unroll
                for (int n = 0; n < 4; ++n)
                    acc[m][n] = __builtin_amdgcn_mfma_f32_16x16x32_bf16(af[m], bfr[n], acc[m][n], 0, 0, 0);
        }
    }

    #pragma unroll
    for (int m = 0; m < 4; ++m) {
        int row0 = m0 + wr * 64 + m * 16 + ((lane >> 4) << 2);
        #pragma unroll
        for (int n = 0; n < 4; ++n) {
            int col = wc * 64 + n * 16 + (lane & 15);
            #pragma unroll
            for (int j = 0; j < 4; ++j)
                atomicAdd(&out[(row0 + j) * U_SZ + col], acc[m][n][j]);
        }
    }
}

extern "C" void kernel_launch(void* const* d_in, const int* in_sizes, int n_in,
                              void* d_out, int out_size, void* d_ws, size_t ws_size,
                              hipStream_t stream) {
    const float* x        = (const float*)d_in[0];
    const float* eps_w    = (const float*)d_in[1];
    const float* eps_b    = (const float*)d_in[2];
    const float* zw_mu    = (const float*)d_in[3];
    const float* zw_sigma = (const float*)d_in[4];
    const float* Wf       = (const float*)d_in[5];
    const float* zb_mu    = (const float*)d_in[6];
    const float* zb_sigma = (const float*)d_in[7];
    const float* Bf       = (const float*)d_in[8];
    const int*   gid      = (const int*)d_in[9];
    float* out = (float*)d_out;

    const size_t WFT_BYTES  = (size_t)K_SZ * U_SZ * 2;            // 4 MB
    const size_t XH_OFF     = WFT_BYTES;
    const size_t XH_BYTES   = (size_t)B_SZ * IN_SZ * 2;           // 2 MB
    const size_t PART_OFF   = XH_OFF + XH_BYTES;
    const size_t PART_BYTES = (size_t)KSPL * B_SZ * U_SZ * 2;     // 16 MB

    if (ws_size >= PART_OFF + PART_BYTES) {
        short*     wfT  = (short*)d_ws;
        short*     xh   = (short*)((char*)d_ws + XH_OFF);
        _Float16*  part = (_Float16*)((char*)d_ws + PART_OFF);
        fmd_prep<<<NTILE + (B_SZ / BM) * 4, 256, 0, stream>>>(Wf, x, wfT, xh);
        fmd_gemm6<<<(B_SZ / BM) * KSPL, 256, 0, stream>>>(
            xh, wfT, zw_mu, zw_sigma, eps_w, gid, part);
        fmd_reduce4<<<(B_SZ * U_SZ) / 2048, 256, 0, stream>>>(
            part, eps_b, zb_mu, zb_sigma, Bf, gid, out);
    } else {
        fmd_bias<<<B_SZ / 2, 256, 0, stream>>>(eps_b, zb_mu, zb_sigma, Bf, gid, out);
        fmd_gemm_legacy<<<(B_SZ / BM) * KSPL, 256, 0, stream>>>(
            x, eps_w, zw_mu, zw_sigma, Wf, gid, out);
    }
}